// Round 13
// baseline (237.403 us; speedup 1.0000x reference)
//
#include <hip/hip_runtime.h>

#define LQ 5376
#define DM 128
#define NH 16
#define NL 3
#define NP 4
#define DH 8

typedef __attribute__((ext_vector_type(8))) short short8;
typedef __attribute__((ext_vector_type(4))) float float4_t;
typedef __attribute__((ext_vector_type(4))) unsigned int uint4_t;
typedef __attribute__((ext_vector_type(4))) unsigned short ushort4_t;

__device__ __forceinline__ unsigned short f2bf(float f) {
    unsigned u = __builtin_bit_cast(unsigned, f);
    unsigned r = (u + 0x7fffu + ((u >> 16) & 1u)) >> 16;
    return (unsigned short)r;
}
__device__ __forceinline__ float bf2f(unsigned short h) {
    return __builtin_bit_cast(float, (unsigned)h << 16);
}

__device__ __forceinline__ void q_to_level(int q, int& l, int& p, int& Hl, int& Wl,
                                           int& wshift) {
    if (q < 4096)      { l = 0; p = q;        Hl = 64; Wl = 64; wshift = 6; }
    else if (q < 5120) { l = 1; p = q - 4096; Hl = 32; Wl = 32; wshift = 5; }
    else               { l = 2; p = q - 5120; Hl = 16; Wl = 16; wshift = 4; }
}

// ---- fused prep: weights repack (blocks 0..415) + feature-map transpose
// (blocks 416..5791, short4-vectorized xh stores) ----
__global__ __launch_bounds__(256) void prep_k(const float* __restrict__ fm1,
                                              const float* __restrict__ fm2,
                                              const float* __restrict__ fm3,
                                              const float* __restrict__ Wv,
                                              const float* __restrict__ Wo,
                                              const float* __restrict__ Wa,
                                              const float* __restrict__ Wout,
                                              unsigned short* __restrict__ xh,
                                              unsigned short* __restrict__ Wvh,
                                              unsigned short* __restrict__ Woa,
                                              unsigned short* __restrict__ Wouth,
                                              unsigned short* __restrict__ Woutl) {
    __shared__ float tile[32][33];
    const int t = threadIdx.x;
    const int bxraw = blockIdx.x;
    if (bxraw < 416) {
        // ---- weights -> [col][k] bf16 (hi/lo only for W_out) ----
        int idx = bxraw * 256 + t;
        int col = idx >> 7;
        int k   = idx & 127;
        if (col < 128) {
            Wvh[col * 128 + k] = f2bf(Wv[k * 128 + col]);
        } else if (col < 512) {
            int c = col - 128;
            Woa[c * 128 + k] = f2bf(Wo[k * 384 + c]);
        } else if (col < 704) {
            int c = col - 512;
            Woa[(384 + c) * 128 + k] = f2bf(Wa[k * 192 + c]);
        } else {
            int c = col - 704;
            float v = Wout[k * 128 + c];
            unsigned short h = f2bf(v);
            Wouth[c * 128 + k] = h;
            Woutl[c * 128 + k] = f2bf(v - bf2f(h));
        }
        return;
    }
    // ---- transpose: decode flat block id -> (bxx, cy, bz) ----
    const int n = bxraw - 416;          // 0..5375
    const int bxx = n % 168;
    const int rem = n / 168;            // 0..31
    const int cy = rem & 3;
    const int bz = rem >> 2;            // 0..7
    const float* fm; int HW, qstart, p0;
    if (bxx < 128)      { fm = fm1; HW = 4096; qstart = 0;    p0 = bxx * 32; }
    else if (bxx < 160) { fm = fm2; HW = 1024; qstart = 4096; p0 = (bxx - 128) * 32; }
    else                { fm = fm3; HW = 256;  qstart = 5120; p0 = (bxx - 160) * 32; }
    const int c0 = cy * 32;
    const int b  = bz;
    const int tx = t & 31;              // spatial
    const int ty = t >> 5;              // channel (8 rows per pass)
    const float* src = fm + ((size_t)(b * DM + c0)) * HW + p0;
#pragma unroll
    for (int k = 0; k < 32; k += 8)
        tile[ty + k][tx] = src[(size_t)(ty + k) * HW + tx];   // tile[ch][sp]
    __syncthreads();
    // vectorized write: thread t -> query pos = t>>3, channels (t&7)*4..+3
    const int pos = t >> 3;
    const int cg  = t & 7;
    ushort4_t v4;
#pragma unroll
    for (int j = 0; j < 4; ++j)
        v4[j] = f2bf(tile[cg * 4 + j][pos]);
    *(ushort4_t*)(xh + ((size_t)(b * LQ + qstart + p0 + pos)) * DM + c0 + cg * 4) = v4;
}

// ---- value = x @ W_val + b_val (bf16 MFMA), repack to head-major valh ----
__global__ __launch_bounds__(256) void value_proj_mfma(const unsigned short* __restrict__ xh,
                                                       const unsigned short* __restrict__ Wvh,
                                                       const float* __restrict__ b_val,
                                                       unsigned short* __restrict__ valh) {
    __shared__ unsigned short vs[64][136];
    const int t = threadIdx.x;
    const int wv = t >> 6;
    const int lane = t & 63;
    const int m = lane & 15, quad = lane >> 4;
    const int q0 = blockIdx.x * 64 + wv * 16;

    short8 ah[4];
    const size_t arow = (size_t)(q0 + m) * DM;
#pragma unroll
    for (int kk = 0; kk < 4; ++kk)
        ah[kk] = *(const short8*)(xh + arow + kk * 32 + quad * 8);
    float4_t acc[8];
#pragma unroll
    for (int tt = 0; tt < 8; ++tt) acc[tt] = (float4_t)(0.f);
#pragma unroll
    for (int tt = 0; tt < 8; ++tt) {
        const size_t brow = (size_t)(tt * 16 + m) * DM;
#pragma unroll
        for (int kk = 0; kk < 4; ++kk) {
            short8 bh = *(const short8*)(Wvh + brow + kk * 32 + quad * 8);
            acc[tt] = __builtin_amdgcn_mfma_f32_16x16x32_bf16(ah[kk], bh, acc[tt], 0, 0, 0);
        }
    }
#pragma unroll
    for (int tt = 0; tt < 8; ++tt) {
        const int col = tt * 16 + m;
        const float bb = b_val[col];
#pragma unroll
        for (int r = 0; r < 4; ++r)
            vs[wv * 16 + quad * 4 + r][col] = f2bf(acc[tt][r] + bb);
    }
    __syncthreads();

    const int bq = blockIdx.x * 64;        // 64 queries, never spans a batch
    const int b = bq / LQ;
    const int pos0 = bq - b * LQ;
    const int h  = t >> 4;
    const int ql = t & 15;
#pragma unroll
    for (int it = 0; it < 4; ++it) {
        const int qloc = it * 16 + ql;
        uint4_t v = *(const uint4_t*)&vs[qloc][h * 8];
        *(uint4_t*)(valh + ((size_t)(h * 8 + b) * LQ + pos0 + qloc) * 8) = v;
    }
}

// ---- fused megakernel: 512 threads, 16 queries/block ----
// Phase A: coef GEMM, 36 col-tiles over 8 waves, coef[head][query][37]
// Phase C: wave-coherent sampling (r10) + REGISTER DIET (r13): no at[12]/
//          off2[12] arrays — softmax max/sum as LDS-read passes, aw exp
//          recomputed in-loop (bitwise-identical), offsets read from LDS.
//          Goal: VGPR 100 -> <=84 to fit 3 blocks/CU (24 waves).
// Phase D: out GEMM, 1 col-tile per wave
// NOTE: NO min-waves arg in __launch_bounds__ — r5-vs-r6 A/B proved a binding
// register cap miscompiles this kernel family. Occupancy via natural pressure.
__global__ __launch_bounds__(512) void sampler_k3(const unsigned short* __restrict__ xh,
                                                  const unsigned short* __restrict__ valh,
                                                  const unsigned short* __restrict__ Woa,
                                                  const float* __restrict__ b_off,
                                                  const float* __restrict__ b_attn,
                                                  const unsigned short* __restrict__ Wouth,
                                                  const unsigned short* __restrict__ Woutl,
                                                  const float* __restrict__ b_out,
                                                  float* __restrict__ out) {
    __shared__ float coef[16][16][37];  // [head][query][0..23 offs, 24..35 logits]
    __shared__ float oh[16][132];
    const int t = threadIdx.x;
    const int wv = t >> 6;              // 0..7
    const int lane = t & 63;
    const int m = lane & 15, quad = lane >> 4;
    // XCD-chunked swizzle: 2688 blocks = 8 batches x 336; XCD i gets batch i.
    const int bid = blockIdx.x;
    const int lb = (bid & 7) * 336 + (bid >> 3);
    const int gq0 = lb * 16;

    // ---- phase A: [offs|logits] = x @ Woa (bf16 MFMA), 36 col-tiles over 8 waves
    {
        short8 af[4];
        const size_t arow = (size_t)(gq0 + m) * DM;
#pragma unroll
        for (int kk = 0; kk < 4; ++kk)
            af[kk] = *(const short8*)(xh + arow + kk * 32 + quad * 8);
#pragma unroll
        for (int tl = 0; tl < 5; ++tl) {
            const int tile4 = wv + (tl << 3);   // waves 0..3 get 5 tiles, 4..7 get 4
            if (tile4 < 36) {
                const int col = tile4 * 16 + m;
                const size_t brow = (size_t)col * DM;
                float4_t acc = (float4_t)(0.f);
#pragma unroll
                for (int kk = 0; kk < 4; ++kk) {
                    short8 bfr = *(const short8*)(Woa + brow + kk * 32 + quad * 8);
                    acc = __builtin_amdgcn_mfma_f32_16x16x32_bf16(af[kk], bfr, acc, 0, 0, 0);
                }
                int hc, jc;
                float bb;
                if (col < 384) { hc = col / 24; jc = col - hc * 24; bb = b_off[col]; }
                else { int cc = col - 384; hc = cc / 12; jc = 24 + cc - hc * 12; bb = b_attn[cc]; }
#pragma unroll
                for (int r = 0; r < 4; ++r)
                    coef[hc][quad * 4 + r][jc] = acc[r] + bb;
            }
        }
    }
    __syncthreads();

    // ---- phase C: softmax via LDS passes + bilinear gather, 2 threads per (q,h)
    // mapping: h = t>>5 (two heads per wave), hf = bit4, qq = t&15
    {
        const int hf = (t >> 4) & 1;
        const int h  = t >> 5;
        const int qq = t & 15;
        const int gq = gq0 + qq;
        const int b  = gq / LQ;
        const int q  = gq - b * LQ;
        int lq, p, Hq, Wq, wshift;
        q_to_level(q, lq, p, Hq, Wq, wshift);
        const float refx = ((p & (Wq - 1)) + 0.5f) / Wq;
        const float refy = ((p >> wshift) + 0.5f) / Hq;

        const float* cf = &coef[h][qq][0];
        // register diet: max and sum as LDS-read passes (same order as before
        // -> bitwise-identical); per-point exp/offsets re-read in the loop.
        float mx = cf[24];
#pragma unroll
        for (int k = 1; k < 12; ++k) mx = fmaxf(mx, cf[24 + k]);
        float s = 0.f;
#pragma unroll
        for (int k = 0; k < 12; ++k) s += __expf(cf[24 + k] - mx);
        const float inv = 1.f / s;

        const unsigned short* vbase = valh + ((size_t)(h * 8 + b) * LQ) * 8;
        float acc[8];
#pragma unroll
        for (int e = 0; e < 8; ++e) acc[e] = 0.f;

#pragma unroll
        for (int jj = 0; jj < 6; ++jj) {
            const int j = hf * 6 + jj;          // global point id 0..11
            const int l = j >> 2;               // level 0..2
            const int Wl = 64 >> l;             // = Hl
            const int start_l = (l == 0) ? 0 : ((l == 1) ? 4096 : 5120);
            const float aw = __expf(cf[24 + hf * 6 + jj] - mx) * inv;
            const float ox = cf[hf * 12 + jj * 2 + 0];
            const float oy = cf[hf * 12 + jj * 2 + 1];
            const float fx = refx * Wl - 0.5f + ox;
            const float fy = refy * Wl - 0.5f + oy;
            const float x0f = floorf(fx);
            const float y0f = floorf(fy);
            const int x0 = (int)x0f;
            const int y0 = (int)y0f;
            const float fx1 = fx - x0f, fy1 = fy - y0f;
            const float gx0 = (x0 >= 0 && x0 < Wl)      ? (1.f - fx1) : 0.f;
            const float gx1 = (x0 >= -1 && x0 < Wl - 1) ? fx1 : 0.f;
            const float gy0 = (y0 >= 0 && y0 < Wl)      ? (1.f - fy1) : 0.f;
            const float gy1 = (y0 >= -1 && y0 < Wl - 1) ? fy1 : 0.f;
            const int xc0 = min(max(x0, 0), Wl - 1);
            const int xc1 = min(max(x0 + 1, 0), Wl - 1);
            const int yc0 = min(max(y0, 0), Wl - 1);
            const int yc1 = min(max(y0 + 1, 0), Wl - 1);
            const int r0 = start_l + yc0 * Wl;
            const int r1 = start_l + yc1 * Wl;
            const uint4_t v00 = *(const uint4_t*)(vbase + (size_t)(r0 + xc0) * 8);
            const uint4_t v01 = *(const uint4_t*)(vbase + (size_t)(r0 + xc1) * 8);
            const uint4_t v10 = *(const uint4_t*)(vbase + (size_t)(r1 + xc0) * 8);
            const uint4_t v11 = *(const uint4_t*)(vbase + (size_t)(r1 + xc1) * 8);
            const float w00 = gx0 * gy0 * aw;
            const float w01 = gx1 * gy0 * aw;
            const float w10 = gx0 * gy1 * aw;
            const float w11 = gx1 * gy1 * aw;
#pragma unroll
            for (int dd = 0; dd < 4; ++dd) {
                acc[dd * 2 + 0] += w00 * __builtin_bit_cast(float, v00[dd] << 16)
                                +  w01 * __builtin_bit_cast(float, v01[dd] << 16)
                                +  w10 * __builtin_bit_cast(float, v10[dd] << 16)
                                +  w11 * __builtin_bit_cast(float, v11[dd] << 16);
                acc[dd * 2 + 1] += w00 * __builtin_bit_cast(float, v00[dd] & 0xffff0000u)
                                +  w01 * __builtin_bit_cast(float, v01[dd] & 0xffff0000u)
                                +  w10 * __builtin_bit_cast(float, v10[dd] & 0xffff0000u)
                                +  w11 * __builtin_bit_cast(float, v11[dd] & 0xffff0000u);
            }
        }
        // pair reduce across the two halves (pairs differ only in bit 4 = hf)
#pragma unroll
        for (int e = 0; e < 8; ++e) acc[e] += __shfl_xor(acc[e], 16, 64);
        // both halves hold full sums; half0 stores ch 0..3, half1 stores ch 4..7
        const int ob = h * 8 + hf * 4;
        oh[qq][ob + 0] = hf ? acc[4] : acc[0];
        oh[qq][ob + 1] = hf ? acc[5] : acc[1];
        oh[qq][ob + 2] = hf ? acc[6] : acc[2];
        oh[qq][ob + 3] = hf ? acc[7] : acc[3];
    }
    __syncthreads();

    // ---- phase D: out = oh @ W_out + b_out (hi/lo MFMA), 1 col-tile per wave
    {
        float4_t acc2 = (float4_t)(0.f);
#pragma unroll
        for (int kk = 0; kk < 4; ++kk) {
            const float4_t a0 = *(const float4_t*)&oh[m][kk * 32 + quad * 8];
            const float4_t a1 = *(const float4_t*)&oh[m][kk * 32 + quad * 8 + 4];
            short8 ahi, alo;
#pragma unroll
            for (int j = 0; j < 8; ++j) {
                const float f = (j < 4) ? a0[j] : a1[j - 4];
                const unsigned short hh = f2bf(f);
                ahi[j] = (short)hh;
                alo[j] = (short)f2bf(f - bf2f(hh));
            }
            const size_t brow = (size_t)(wv * 16 + m) * DM + kk * 32 + quad * 8;
            short8 bh = *(const short8*)(Wouth + brow);
            short8 bl = *(const short8*)(Woutl + brow);
            acc2 = __builtin_amdgcn_mfma_f32_16x16x32_bf16(ahi, bh, acc2, 0, 0, 0);
            acc2 = __builtin_amdgcn_mfma_f32_16x16x32_bf16(alo, bh, acc2, 0, 0, 0);
            acc2 = __builtin_amdgcn_mfma_f32_16x16x32_bf16(ahi, bl, acc2, 0, 0, 0);
        }
        const size_t lvl_base[3] = {0, 4194304, 5242880};
        const int col = wv * 16 + m;
        const float bb = b_out[col];
#pragma unroll
        for (int r = 0; r < 4; ++r) {
            const int qq = quad * 4 + r;
            const int gq = gq0 + qq;
            const int b = gq / LQ;
            const int q = gq - b * LQ;
            int lq, p, Hq, Wq, wshift;
            q_to_level(q, lq, p, Hq, Wq, wshift);
            const int HWq = Hq * Wq;
            out[lvl_base[lq] + ((size_t)(b * DM + col)) * HWq + p] = acc2[r] + bb;
        }
    }
}

extern "C" void kernel_launch(void* const* d_in, const int* in_sizes, int n_in,
                              void* d_out, int out_size, void* d_ws, size_t ws_size,
                              hipStream_t stream) {
    const float* fm1    = (const float*)d_in[0];
    const float* fm2    = (const float*)d_in[1];
    const float* fm3    = (const float*)d_in[2];
    const float* W_off  = (const float*)d_in[3];
    const float* b_off  = (const float*)d_in[4];
    const float* W_attn = (const float*)d_in[5];
    const float* b_attn = (const float*)d_in[6];
    const float* W_val  = (const float*)d_in[7];
    const float* b_val  = (const float*)d_in[8];
    const float* W_out  = (const float*)d_in[9];
    const float* b_out  = (const float*)d_in[10];
    float* out = (float*)d_out;

    const size_t NQ = (size_t)8 * LQ;          // 43008
    unsigned short* xh    = (unsigned short*)d_ws;      // 11,010,048 B
    unsigned short* valh  = xh + NQ * DM;               // 11,010,048 B (head-major)
    unsigned short* Wvh   = valh + NQ * DM;             // 32 KB
    unsigned short* Woa   = Wvh + 128 * 128;            // 144 KB
    unsigned short* Wouth = Woa + 576 * 128;
    unsigned short* Woutl = Wouth + 128 * 128;

    prep_k<<<5792, 256, 0, stream>>>(fm1, fm2, fm3, W_val, W_off, W_attn, W_out,
                                     xh, Wvh, Woa, Wouth, Woutl);

    value_proj_mfma<<<672, 256, 0, stream>>>(xh, Wvh, b_val, valh);

    sampler_k3<<<2688, 512, 0, stream>>>(xh, valh, Woa, b_off, b_attn,
                                         Wouth, Woutl, b_out, out);
}

// Round 15
// 234.696 us; speedup vs baseline: 1.0115x; 1.0115x over previous
//
#include <hip/hip_runtime.h>

#define LQ 5376
#define DM 128
#define NH 16
#define NL 3
#define NP 4
#define DH 8

typedef __attribute__((ext_vector_type(8))) short short8;
typedef __attribute__((ext_vector_type(4))) float float4_t;
typedef __attribute__((ext_vector_type(4))) unsigned int uint4_t;
typedef __attribute__((ext_vector_type(4))) unsigned short ushort4_t;

__device__ __forceinline__ unsigned short f2bf(float f) {
    unsigned u = __builtin_bit_cast(unsigned, f);
    unsigned r = (u + 0x7fffu + ((u >> 16) & 1u)) >> 16;
    return (unsigned short)r;
}
__device__ __forceinline__ float bf2f(unsigned short h) {
    return __builtin_bit_cast(float, (unsigned)h << 16);
}

__device__ __forceinline__ void q_to_level(int q, int& l, int& p, int& Hl, int& Wl,
                                           int& wshift) {
    if (q < 4096)      { l = 0; p = q;        Hl = 64; Wl = 64; wshift = 6; }
    else if (q < 5120) { l = 1; p = q - 4096; Hl = 32; Wl = 32; wshift = 5; }
    else               { l = 2; p = q - 5120; Hl = 16; Wl = 16; wshift = 4; }
}

// ---- fused prep: weights repack (blocks 0..415) + feature-map transpose
// (blocks 416..5791, short4-vectorized xh stores) ----
__global__ __launch_bounds__(256) void prep_k(const float* __restrict__ fm1,
                                              const float* __restrict__ fm2,
                                              const float* __restrict__ fm3,
                                              const float* __restrict__ Wv,
                                              const float* __restrict__ Wo,
                                              const float* __restrict__ Wa,
                                              const float* __restrict__ Wout,
                                              unsigned short* __restrict__ xh,
                                              unsigned short* __restrict__ Wvh,
                                              unsigned short* __restrict__ Woa,
                                              unsigned short* __restrict__ Wouth,
                                              unsigned short* __restrict__ Woutl) {
    __shared__ float tile[32][33];
    const int t = threadIdx.x;
    const int bxraw = blockIdx.x;
    if (bxraw < 416) {
        // ---- weights -> [col][k] bf16 (hi/lo only for W_out) ----
        int idx = bxraw * 256 + t;
        int col = idx >> 7;
        int k   = idx & 127;
        if (col < 128) {
            Wvh[col * 128 + k] = f2bf(Wv[k * 128 + col]);
        } else if (col < 512) {
            int c = col - 128;
            Woa[c * 128 + k] = f2bf(Wo[k * 384 + c]);
        } else if (col < 704) {
            int c = col - 512;
            Woa[(384 + c) * 128 + k] = f2bf(Wa[k * 192 + c]);
        } else {
            int c = col - 704;
            float v = Wout[k * 128 + c];
            unsigned short h = f2bf(v);
            Wouth[c * 128 + k] = h;
            Woutl[c * 128 + k] = f2bf(v - bf2f(h));
        }
        return;
    }
    // ---- transpose: decode flat block id -> (bxx, cy, bz) ----
    const int n = bxraw - 416;          // 0..5375
    const int bxx = n % 168;
    const int rem = n / 168;            // 0..31
    const int cy = rem & 3;
    const int bz = rem >> 2;            // 0..7
    const float* fm; int HW, qstart, p0;
    if (bxx < 128)      { fm = fm1; HW = 4096; qstart = 0;    p0 = bxx * 32; }
    else if (bxx < 160) { fm = fm2; HW = 1024; qstart = 4096; p0 = (bxx - 128) * 32; }
    else                { fm = fm3; HW = 256;  qstart = 5120; p0 = (bxx - 160) * 32; }
    const int c0 = cy * 32;
    const int b  = bz;
    const int tx = t & 31;              // spatial
    const int ty = t >> 5;              // channel (8 rows per pass)
    const float* src = fm + ((size_t)(b * DM + c0)) * HW + p0;
#pragma unroll
    for (int k = 0; k < 32; k += 8)
        tile[ty + k][tx] = src[(size_t)(ty + k) * HW + tx];   // tile[ch][sp]
    __syncthreads();
    // vectorized write: thread t -> query pos = t>>3, channels (t&7)*4..+3
    const int pos = t >> 3;
    const int cg  = t & 7;
    ushort4_t v4;
#pragma unroll
    for (int j = 0; j < 4; ++j)
        v4[j] = f2bf(tile[cg * 4 + j][pos]);
    *(ushort4_t*)(xh + ((size_t)(b * LQ + qstart + p0 + pos)) * DM + c0 + cg * 4) = v4;
}

// ---- value = x @ W_val + b_val (bf16 MFMA), repack to head-major valh ----
__global__ __launch_bounds__(256) void value_proj_mfma(const unsigned short* __restrict__ xh,
                                                       const unsigned short* __restrict__ Wvh,
                                                       const float* __restrict__ b_val,
                                                       unsigned short* __restrict__ valh) {
    __shared__ unsigned short vs[64][136];
    const int t = threadIdx.x;
    const int wv = t >> 6;
    const int lane = t & 63;
    const int m = lane & 15, quad = lane >> 4;
    const int q0 = blockIdx.x * 64 + wv * 16;

    short8 ah[4];
    const size_t arow = (size_t)(q0 + m) * DM;
#pragma unroll
    for (int kk = 0; kk < 4; ++kk)
        ah[kk] = *(const short8*)(xh + arow + kk * 32 + quad * 8);
    float4_t acc[8];
#pragma unroll
    for (int tt = 0; tt < 8; ++tt) acc[tt] = (float4_t)(0.f);
#pragma unroll
    for (int tt = 0; tt < 8; ++tt) {
        const size_t brow = (size_t)(tt * 16 + m) * DM;
#pragma unroll
        for (int kk = 0; kk < 4; ++kk) {
            short8 bh = *(const short8*)(Wvh + brow + kk * 32 + quad * 8);
            acc[tt] = __builtin_amdgcn_mfma_f32_16x16x32_bf16(ah[kk], bh, acc[tt], 0, 0, 0);
        }
    }
#pragma unroll
    for (int tt = 0; tt < 8; ++tt) {
        const int col = tt * 16 + m;
        const float bb = b_val[col];
#pragma unroll
        for (int r = 0; r < 4; ++r)
            vs[wv * 16 + quad * 4 + r][col] = f2bf(acc[tt][r] + bb);
    }
    __syncthreads();

    const int bq = blockIdx.x * 64;        // 64 queries, never spans a batch
    const int b = bq / LQ;
    const int pos0 = bq - b * LQ;
    const int h  = t >> 4;
    const int ql = t & 15;
#pragma unroll
    for (int it = 0; it < 4; ++it) {
        const int qloc = it * 16 + ql;
        uint4_t v = *(const uint4_t*)&vs[qloc][h * 8];
        *(uint4_t*)(valh + ((size_t)(h * 8 + b) * LQ + pos0 + qloc) * 8) = v;
    }
}

// ---- fused megakernel (r10/r12-verified, 137 us): 512 threads, 16 queries/block ----
// Phase A: coef GEMM, 36 col-tiles over 8 waves, coef[head][query][37]
// Phase C: wave-coherent sampling (h = t>>5: 16 consecutive lanes = 16
//          consecutive queries, same head/point -> few cache lines per gather)
// Phase D: out GEMM, 1 col-tile per wave
// NOTE: NO min-waves arg in __launch_bounds__, and NO masked/partial-row
// variants — both correlated with correctness failures in this kernel family
// (r2/r3/r5/r14 failed; r8/r10/r12 passed). Occupancy via natural pressure.
__global__ __launch_bounds__(512) void sampler_k3(const unsigned short* __restrict__ xh,
                                                  const unsigned short* __restrict__ valh,
                                                  const unsigned short* __restrict__ Woa,
                                                  const float* __restrict__ b_off,
                                                  const float* __restrict__ b_attn,
                                                  const unsigned short* __restrict__ Wouth,
                                                  const unsigned short* __restrict__ Woutl,
                                                  const float* __restrict__ b_out,
                                                  float* __restrict__ out) {
    __shared__ float coef[16][16][37];  // [head][query][0..23 offs, 24..35 logits]
    __shared__ float oh[16][132];
    const int t = threadIdx.x;
    const int wv = t >> 6;              // 0..7
    const int lane = t & 63;
    const int m = lane & 15, quad = lane >> 4;
    // XCD-chunked swizzle: 2688 blocks = 8 batches x 336; XCD i gets batch i.
    const int bid = blockIdx.x;
    const int lb = (bid & 7) * 336 + (bid >> 3);
    const int gq0 = lb * 16;

    // ---- phase A: [offs|logits] = x @ Woa (bf16 MFMA), 36 col-tiles over 8 waves
    {
        short8 af[4];
        const size_t arow = (size_t)(gq0 + m) * DM;
#pragma unroll
        for (int kk = 0; kk < 4; ++kk)
            af[kk] = *(const short8*)(xh + arow + kk * 32 + quad * 8);
#pragma unroll
        for (int tl = 0; tl < 5; ++tl) {
            const int tile4 = wv + (tl << 3);   // waves 0..3 get 5 tiles, 4..7 get 4
            if (tile4 < 36) {
                const int col = tile4 * 16 + m;
                const size_t brow = (size_t)col * DM;
                float4_t acc = (float4_t)(0.f);
#pragma unroll
                for (int kk = 0; kk < 4; ++kk) {
                    short8 bfr = *(const short8*)(Woa + brow + kk * 32 + quad * 8);
                    acc = __builtin_amdgcn_mfma_f32_16x16x32_bf16(af[kk], bfr, acc, 0, 0, 0);
                }
                int hc, jc;
                float bb;
                if (col < 384) { hc = col / 24; jc = col - hc * 24; bb = b_off[col]; }
                else { int cc = col - 384; hc = cc / 12; jc = 24 + cc - hc * 12; bb = b_attn[cc]; }
#pragma unroll
                for (int r = 0; r < 4; ++r)
                    coef[hc][quad * 4 + r][jc] = acc[r] + bb;
            }
        }
    }
    __syncthreads();

    // ---- phase C: softmax in regs + bilinear gather, 2 threads per (q,h)
    // mapping: h = t>>5 (two heads per wave), hf = bit4, qq = t&15
    {
        const int hf = (t >> 4) & 1;
        const int h  = t >> 5;
        const int qq = t & 15;
        const int gq = gq0 + qq;
        const int b  = gq / LQ;
        const int q  = gq - b * LQ;
        int lq, p, Hq, Wq, wshift;
        q_to_level(q, lq, p, Hq, Wq, wshift);
        const float refx = ((p & (Wq - 1)) + 0.5f) / Wq;
        const float refy = ((p >> wshift) + 0.5f) / Hq;

        const float* cf = &coef[h][qq][0];
        float at[12];
#pragma unroll
        for (int k = 0; k < 12; ++k) at[k] = cf[24 + k];
        float off2[12];
#pragma unroll
        for (int k = 0; k < 12; ++k) off2[k] = cf[hf * 12 + k];
        // softmax over 12 (redundant in both halves, static indices)
        float mx = at[0];
#pragma unroll
        for (int k = 1; k < 12; ++k) mx = fmaxf(mx, at[k]);
        float s = 0.f;
#pragma unroll
        for (int k = 0; k < 12; ++k) { at[k] = __expf(at[k] - mx); s += at[k]; }
        const float inv = 1.f / s;

        const unsigned short* vbase = valh + ((size_t)(h * 8 + b) * LQ) * 8;
        float acc[8];
#pragma unroll
        for (int e = 0; e < 8; ++e) acc[e] = 0.f;

#pragma unroll
        for (int jj = 0; jj < 6; ++jj) {
            const int j = hf * 6 + jj;          // global point id 0..11
            const int l = j >> 2;               // level 0..2
            const int Wl = 64 >> l;             // = Hl
            const int start_l = (l == 0) ? 0 : ((l == 1) ? 4096 : 5120);
            const float aw = (hf ? at[jj + 6] : at[jj]) * inv;
            const float ox = off2[jj * 2 + 0];
            const float oy = off2[jj * 2 + 1];
            const float fx = refx * Wl - 0.5f + ox;
            const float fy = refy * Wl - 0.5f + oy;
            const float x0f = floorf(fx);
            const float y0f = floorf(fy);
            const int x0 = (int)x0f;
            const int y0 = (int)y0f;
            const float fx1 = fx - x0f, fy1 = fy - y0f;
            const float gx0 = (x0 >= 0 && x0 < Wl)      ? (1.f - fx1) : 0.f;
            const float gx1 = (x0 >= -1 && x0 < Wl - 1) ? fx1 : 0.f;
            const float gy0 = (y0 >= 0 && y0 < Wl)      ? (1.f - fy1) : 0.f;
            const float gy1 = (y0 >= -1 && y0 < Wl - 1) ? fy1 : 0.f;
            const int xc0 = min(max(x0, 0), Wl - 1);
            const int xc1 = min(max(x0 + 1, 0), Wl - 1);
            const int yc0 = min(max(y0, 0), Wl - 1);
            const int yc1 = min(max(y0 + 1, 0), Wl - 1);
            const int r0 = start_l + yc0 * Wl;
            const int r1 = start_l + yc1 * Wl;
            const uint4_t v00 = *(const uint4_t*)(vbase + (size_t)(r0 + xc0) * 8);
            const uint4_t v01 = *(const uint4_t*)(vbase + (size_t)(r0 + xc1) * 8);
            const uint4_t v10 = *(const uint4_t*)(vbase + (size_t)(r1 + xc0) * 8);
            const uint4_t v11 = *(const uint4_t*)(vbase + (size_t)(r1 + xc1) * 8);
            const float w00 = gx0 * gy0 * aw;
            const float w01 = gx1 * gy0 * aw;
            const float w10 = gx0 * gy1 * aw;
            const float w11 = gx1 * gy1 * aw;
#pragma unroll
            for (int dd = 0; dd < 4; ++dd) {
                acc[dd * 2 + 0] += w00 * __builtin_bit_cast(float, v00[dd] << 16)
                                +  w01 * __builtin_bit_cast(float, v01[dd] << 16)
                                +  w10 * __builtin_bit_cast(float, v10[dd] << 16)
                                +  w11 * __builtin_bit_cast(float, v11[dd] << 16);
                acc[dd * 2 + 1] += w00 * __builtin_bit_cast(float, v00[dd] & 0xffff0000u)
                                +  w01 * __builtin_bit_cast(float, v01[dd] & 0xffff0000u)
                                +  w10 * __builtin_bit_cast(float, v10[dd] & 0xffff0000u)
                                +  w11 * __builtin_bit_cast(float, v11[dd] & 0xffff0000u);
            }
        }
        // pair reduce across the two halves (pairs differ only in bit 4 = hf)
#pragma unroll
        for (int e = 0; e < 8; ++e) acc[e] += __shfl_xor(acc[e], 16, 64);
        // both halves hold full sums; half0 stores ch 0..3, half1 stores ch 4..7
        const int ob = h * 8 + hf * 4;
        oh[qq][ob + 0] = hf ? acc[4] : acc[0];
        oh[qq][ob + 1] = hf ? acc[5] : acc[1];
        oh[qq][ob + 2] = hf ? acc[6] : acc[2];
        oh[qq][ob + 3] = hf ? acc[7] : acc[3];
    }
    __syncthreads();

    // ---- phase D: out = oh @ W_out + b_out (hi/lo MFMA), 1 col-tile per wave
    {
        float4_t acc2 = (float4_t)(0.f);
#pragma unroll
        for (int kk = 0; kk < 4; ++kk) {
            const float4_t a0 = *(const float4_t*)&oh[m][kk * 32 + quad * 8];
            const float4_t a1 = *(const float4_t*)&oh[m][kk * 32 + quad * 8 + 4];
            short8 ahi, alo;
#pragma unroll
            for (int j = 0; j < 8; ++j) {
                const float f = (j < 4) ? a0[j] : a1[j - 4];
                const unsigned short hh = f2bf(f);
                ahi[j] = (short)hh;
                alo[j] = (short)f2bf(f - bf2f(hh));
            }
            const size_t brow = (size_t)(wv * 16 + m) * DM + kk * 32 + quad * 8;
            short8 bh = *(const short8*)(Wouth + brow);
            short8 bl = *(const short8*)(Woutl + brow);
            acc2 = __builtin_amdgcn_mfma_f32_16x16x32_bf16(ahi, bh, acc2, 0, 0, 0);
            acc2 = __builtin_amdgcn_mfma_f32_16x16x32_bf16(alo, bh, acc2, 0, 0, 0);
            acc2 = __builtin_amdgcn_mfma_f32_16x16x32_bf16(ahi, bl, acc2, 0, 0, 0);
        }
        const size_t lvl_base[3] = {0, 4194304, 5242880};
        const int col = wv * 16 + m;
        const float bb = b_out[col];
#pragma unroll
        for (int r = 0; r < 4; ++r) {
            const int qq = quad * 4 + r;
            const int gq = gq0 + qq;
            const int b = gq / LQ;
            const int q = gq - b * LQ;
            int lq, p, Hq, Wq, wshift;
            q_to_level(q, lq, p, Hq, Wq, wshift);
            const int HWq = Hq * Wq;
            out[lvl_base[lq] + ((size_t)(b * DM + col)) * HWq + p] = acc2[r] + bb;
        }
    }
}

extern "C" void kernel_launch(void* const* d_in, const int* in_sizes, int n_in,
                              void* d_out, int out_size, void* d_ws, size_t ws_size,
                              hipStream_t stream) {
    const float* fm1    = (const float*)d_in[0];
    const float* fm2    = (const float*)d_in[1];
    const float* fm3    = (const float*)d_in[2];
    const float* W_off  = (const float*)d_in[3];
    const float* b_off  = (const float*)d_in[4];
    const float* W_attn = (const float*)d_in[5];
    const float* b_attn = (const float*)d_in[6];
    const float* W_val  = (const float*)d_in[7];
    const float* b_val  = (const float*)d_in[8];
    const float* W_out  = (const float*)d_in[9];
    const float* b_out  = (const float*)d_in[10];
    float* out = (float*)d_out;

    const size_t NQ = (size_t)8 * LQ;          // 43008
    unsigned short* xh    = (unsigned short*)d_ws;      // 11,010,048 B
    unsigned short* valh  = xh + NQ * DM;               // 11,010,048 B (head-major)
    unsigned short* Wvh   = valh + NQ * DM;             // 32 KB
    unsigned short* Woa   = Wvh + 128 * 128;            // 144 KB
    unsigned short* Wouth = Woa + 576 * 128;
    unsigned short* Woutl = Wouth + 128 * 128;

    prep_k<<<5792, 256, 0, stream>>>(fm1, fm2, fm3, W_val, W_off, W_attn, W_out,
                                     xh, Wvh, Woa, Wouth, Woutl);

    value_proj_mfma<<<672, 256, 0, stream>>>(xh, Wvh, b_val, valh);

    sampler_k3<<<2688, 512, 0, stream>>>(xh, valh, Woa, b_off, b_attn,
                                         Wouth, Woutl, b_out, out);
}

// Round 16
// 233.679 us; speedup vs baseline: 1.0159x; 1.0044x over previous
//
#include <hip/hip_runtime.h>

#define LQ 5376
#define DM 128
#define NH 16
#define NL 3
#define NP 4
#define DH 8

typedef __attribute__((ext_vector_type(8))) short short8;
typedef __attribute__((ext_vector_type(4))) float float4_t;
typedef __attribute__((ext_vector_type(4))) unsigned int uint4_t;
typedef __attribute__((ext_vector_type(4))) unsigned short ushort4_t;

__device__ __forceinline__ unsigned short f2bf(float f) {
    unsigned u = __builtin_bit_cast(unsigned, f);
    unsigned r = (u + 0x7fffu + ((u >> 16) & 1u)) >> 16;
    return (unsigned short)r;
}
__device__ __forceinline__ float bf2f(unsigned short h) {
    return __builtin_bit_cast(float, (unsigned)h << 16);
}

__device__ __forceinline__ void q_to_level(int q, int& l, int& p, int& Hl, int& Wl,
                                           int& wshift) {
    if (q < 4096)      { l = 0; p = q;        Hl = 64; Wl = 64; wshift = 6; }
    else if (q < 5120) { l = 1; p = q - 4096; Hl = 32; Wl = 32; wshift = 5; }
    else               { l = 2; p = q - 5120; Hl = 16; Wl = 16; wshift = 4; }
}

// ---- fused prep: weights repack (blocks 0..415) + feature-map transpose
// (blocks 416..5791, short4-vectorized xh stores) ----
__global__ __launch_bounds__(256) void prep_k(const float* __restrict__ fm1,
                                              const float* __restrict__ fm2,
                                              const float* __restrict__ fm3,
                                              const float* __restrict__ Wv,
                                              const float* __restrict__ Wo,
                                              const float* __restrict__ Wa,
                                              const float* __restrict__ Wout,
                                              unsigned short* __restrict__ xh,
                                              unsigned short* __restrict__ Wvh,
                                              unsigned short* __restrict__ Woa,
                                              unsigned short* __restrict__ Wouth,
                                              unsigned short* __restrict__ Woutl) {
    __shared__ float tile[32][33];
    const int t = threadIdx.x;
    const int bxraw = blockIdx.x;
    if (bxraw < 416) {
        // ---- weights -> [col][k] bf16 (hi/lo only for W_out) ----
        int idx = bxraw * 256 + t;
        int col = idx >> 7;
        int k   = idx & 127;
        if (col < 128) {
            Wvh[col * 128 + k] = f2bf(Wv[k * 128 + col]);
        } else if (col < 512) {
            int c = col - 128;
            Woa[c * 128 + k] = f2bf(Wo[k * 384 + c]);
        } else if (col < 704) {
            int c = col - 512;
            Woa[(384 + c) * 128 + k] = f2bf(Wa[k * 192 + c]);
        } else {
            int c = col - 704;
            float v = Wout[k * 128 + c];
            unsigned short h = f2bf(v);
            Wouth[c * 128 + k] = h;
            Woutl[c * 128 + k] = f2bf(v - bf2f(h));
        }
        return;
    }
    // ---- transpose: decode flat block id -> (bxx, cy, bz) ----
    const int n = bxraw - 416;          // 0..5375
    const int bxx = n % 168;
    const int rem = n / 168;            // 0..31
    const int cy = rem & 3;
    const int bz = rem >> 2;            // 0..7
    const float* fm; int HW, qstart, p0;
    if (bxx < 128)      { fm = fm1; HW = 4096; qstart = 0;    p0 = bxx * 32; }
    else if (bxx < 160) { fm = fm2; HW = 1024; qstart = 4096; p0 = (bxx - 128) * 32; }
    else                { fm = fm3; HW = 256;  qstart = 5120; p0 = (bxx - 160) * 32; }
    const int c0 = cy * 32;
    const int b  = bz;
    const int tx = t & 31;              // spatial
    const int ty = t >> 5;              // channel (8 rows per pass)
    const float* src = fm + ((size_t)(b * DM + c0)) * HW + p0;
#pragma unroll
    for (int k = 0; k < 32; k += 8)
        tile[ty + k][tx] = src[(size_t)(ty + k) * HW + tx];   // tile[ch][sp]
    __syncthreads();
    // vectorized write: thread t -> query pos = t>>3, channels (t&7)*4..+3
    const int pos = t >> 3;
    const int cg  = t & 7;
    ushort4_t v4;
#pragma unroll
    for (int j = 0; j < 4; ++j)
        v4[j] = f2bf(tile[cg * 4 + j][pos]);
    *(ushort4_t*)(xh + ((size_t)(b * LQ + qstart + p0 + pos)) * DM + c0 + cg * 4) = v4;
}

// ---- value = x @ W_val + b_val (bf16 MFMA), repack to head-major valh ----
__global__ __launch_bounds__(256) void value_proj_mfma(const unsigned short* __restrict__ xh,
                                                       const unsigned short* __restrict__ Wvh,
                                                       const float* __restrict__ b_val,
                                                       unsigned short* __restrict__ valh) {
    __shared__ unsigned short vs[64][136];
    const int t = threadIdx.x;
    const int wv = t >> 6;
    const int lane = t & 63;
    const int m = lane & 15, quad = lane >> 4;
    const int q0 = blockIdx.x * 64 + wv * 16;

    short8 ah[4];
    const size_t arow = (size_t)(q0 + m) * DM;
#pragma unroll
    for (int kk = 0; kk < 4; ++kk)
        ah[kk] = *(const short8*)(xh + arow + kk * 32 + quad * 8);
    float4_t acc[8];
#pragma unroll
    for (int tt = 0; tt < 8; ++tt) acc[tt] = (float4_t)(0.f);
#pragma unroll
    for (int tt = 0; tt < 8; ++tt) {
        const size_t brow = (size_t)(tt * 16 + m) * DM;
#pragma unroll
        for (int kk = 0; kk < 4; ++kk) {
            short8 bh = *(const short8*)(Wvh + brow + kk * 32 + quad * 8);
            acc[tt] = __builtin_amdgcn_mfma_f32_16x16x32_bf16(ah[kk], bh, acc[tt], 0, 0, 0);
        }
    }
#pragma unroll
    for (int tt = 0; tt < 8; ++tt) {
        const int col = tt * 16 + m;
        const float bb = b_val[col];
#pragma unroll
        for (int r = 0; r < 4; ++r)
            vs[wv * 16 + quad * 4 + r][col] = f2bf(acc[tt][r] + bb);
    }
    __syncthreads();

    const int bq = blockIdx.x * 64;        // 64 queries, never spans a batch
    const int b = bq / LQ;
    const int pos0 = bq - b * LQ;
    const int h  = t >> 4;
    const int ql = t & 15;
#pragma unroll
    for (int it = 0; it < 4; ++it) {
        const int qloc = it * 16 + ql;
        uint4_t v = *(const uint4_t*)&vs[qloc][h * 8];
        *(uint4_t*)(valh + ((size_t)(h * 8 + b) * LQ + pos0 + qloc) * 8) = v;
    }
}

// ---- fused megakernel (r10/r12/r15-verified body): 512 threads, 16 q/block ----
// Phase A: coef GEMM, 36 col-tiles over 8 waves, coef[head][query][37]
// Phase C: wave-coherent sampling, wrapped in s_setprio(1)/(0): with 2
//          desynchronized blocks/CU, prioritizes gather-phase waves' VMEM
//          issue over the other block's phase-A B-loads (runtime hint only —
//          cannot affect correctness).
// Phase D: out GEMM, 1 col-tile per wave
// NOTE: NO min-waves arg in __launch_bounds__, and NO masked/partial-row
// variants — both correlated with correctness failures in this kernel family
// (r2/r3/r5/r14 failed; r8/r10/r12/r15 passed). Occupancy via natural pressure.
__global__ __launch_bounds__(512) void sampler_k3(const unsigned short* __restrict__ xh,
                                                  const unsigned short* __restrict__ valh,
                                                  const unsigned short* __restrict__ Woa,
                                                  const float* __restrict__ b_off,
                                                  const float* __restrict__ b_attn,
                                                  const unsigned short* __restrict__ Wouth,
                                                  const unsigned short* __restrict__ Woutl,
                                                  const float* __restrict__ b_out,
                                                  float* __restrict__ out) {
    __shared__ float coef[16][16][37];  // [head][query][0..23 offs, 24..35 logits]
    __shared__ float oh[16][132];
    const int t = threadIdx.x;
    const int wv = t >> 6;              // 0..7
    const int lane = t & 63;
    const int m = lane & 15, quad = lane >> 4;
    // XCD-chunked swizzle: 2688 blocks = 8 batches x 336; XCD i gets batch i.
    const int bid = blockIdx.x;
    const int lb = (bid & 7) * 336 + (bid >> 3);
    const int gq0 = lb * 16;

    // ---- phase A: [offs|logits] = x @ Woa (bf16 MFMA), 36 col-tiles over 8 waves
    {
        short8 af[4];
        const size_t arow = (size_t)(gq0 + m) * DM;
#pragma unroll
        for (int kk = 0; kk < 4; ++kk)
            af[kk] = *(const short8*)(xh + arow + kk * 32 + quad * 8);
#pragma unroll
        for (int tl = 0; tl < 5; ++tl) {
            const int tile4 = wv + (tl << 3);   // waves 0..3 get 5 tiles, 4..7 get 4
            if (tile4 < 36) {
                const int col = tile4 * 16 + m;
                const size_t brow = (size_t)col * DM;
                float4_t acc = (float4_t)(0.f);
#pragma unroll
                for (int kk = 0; kk < 4; ++kk) {
                    short8 bfr = *(const short8*)(Woa + brow + kk * 32 + quad * 8);
                    acc = __builtin_amdgcn_mfma_f32_16x16x32_bf16(af[kk], bfr, acc, 0, 0, 0);
                }
                int hc, jc;
                float bb;
                if (col < 384) { hc = col / 24; jc = col - hc * 24; bb = b_off[col]; }
                else { int cc = col - 384; hc = cc / 12; jc = 24 + cc - hc * 12; bb = b_attn[cc]; }
#pragma unroll
                for (int r = 0; r < 4; ++r)
                    coef[hc][quad * 4 + r][jc] = acc[r] + bb;
            }
        }
    }
    __syncthreads();

    // ---- phase C: softmax in regs + bilinear gather, 2 threads per (q,h)
    // mapping: h = t>>5 (two heads per wave), hf = bit4, qq = t&15
    {
        __builtin_amdgcn_s_setprio(1);
        const int hf = (t >> 4) & 1;
        const int h  = t >> 5;
        const int qq = t & 15;
        const int gq = gq0 + qq;
        const int b  = gq / LQ;
        const int q  = gq - b * LQ;
        int lq, p, Hq, Wq, wshift;
        q_to_level(q, lq, p, Hq, Wq, wshift);
        const float refx = ((p & (Wq - 1)) + 0.5f) / Wq;
        const float refy = ((p >> wshift) + 0.5f) / Hq;

        const float* cf = &coef[h][qq][0];
        float at[12];
#pragma unroll
        for (int k = 0; k < 12; ++k) at[k] = cf[24 + k];
        float off2[12];
#pragma unroll
        for (int k = 0; k < 12; ++k) off2[k] = cf[hf * 12 + k];
        // softmax over 12 (redundant in both halves, static indices)
        float mx = at[0];
#pragma unroll
        for (int k = 1; k < 12; ++k) mx = fmaxf(mx, at[k]);
        float s = 0.f;
#pragma unroll
        for (int k = 0; k < 12; ++k) { at[k] = __expf(at[k] - mx); s += at[k]; }
        const float inv = 1.f / s;

        const unsigned short* vbase = valh + ((size_t)(h * 8 + b) * LQ) * 8;
        float acc[8];
#pragma unroll
        for (int e = 0; e < 8; ++e) acc[e] = 0.f;

#pragma unroll
        for (int jj = 0; jj < 6; ++jj) {
            const int j = hf * 6 + jj;          // global point id 0..11
            const int l = j >> 2;               // level 0..2
            const int Wl = 64 >> l;             // = Hl
            const int start_l = (l == 0) ? 0 : ((l == 1) ? 4096 : 5120);
            const float aw = (hf ? at[jj + 6] : at[jj]) * inv;
            const float ox = off2[jj * 2 + 0];
            const float oy = off2[jj * 2 + 1];
            const float fx = refx * Wl - 0.5f + ox;
            const float fy = refy * Wl - 0.5f + oy;
            const float x0f = floorf(fx);
            const float y0f = floorf(fy);
            const int x0 = (int)x0f;
            const int y0 = (int)y0f;
            const float fx1 = fx - x0f, fy1 = fy - y0f;
            const float gx0 = (x0 >= 0 && x0 < Wl)      ? (1.f - fx1) : 0.f;
            const float gx1 = (x0 >= -1 && x0 < Wl - 1) ? fx1 : 0.f;
            const float gy0 = (y0 >= 0 && y0 < Wl)      ? (1.f - fy1) : 0.f;
            const float gy1 = (y0 >= -1 && y0 < Wl - 1) ? fy1 : 0.f;
            const int xc0 = min(max(x0, 0), Wl - 1);
            const int xc1 = min(max(x0 + 1, 0), Wl - 1);
            const int yc0 = min(max(y0, 0), Wl - 1);
            const int yc1 = min(max(y0 + 1, 0), Wl - 1);
            const int r0 = start_l + yc0 * Wl;
            const int r1 = start_l + yc1 * Wl;
            const uint4_t v00 = *(const uint4_t*)(vbase + (size_t)(r0 + xc0) * 8);
            const uint4_t v01 = *(const uint4_t*)(vbase + (size_t)(r0 + xc1) * 8);
            const uint4_t v10 = *(const uint4_t*)(vbase + (size_t)(r1 + xc0) * 8);
            const uint4_t v11 = *(const uint4_t*)(vbase + (size_t)(r1 + xc1) * 8);
            const float w00 = gx0 * gy0 * aw;
            const float w01 = gx1 * gy0 * aw;
            const float w10 = gx0 * gy1 * aw;
            const float w11 = gx1 * gy1 * aw;
#pragma unroll
            for (int dd = 0; dd < 4; ++dd) {
                acc[dd * 2 + 0] += w00 * __builtin_bit_cast(float, v00[dd] << 16)
                                +  w01 * __builtin_bit_cast(float, v01[dd] << 16)
                                +  w10 * __builtin_bit_cast(float, v10[dd] << 16)
                                +  w11 * __builtin_bit_cast(float, v11[dd] << 16);
                acc[dd * 2 + 1] += w00 * __builtin_bit_cast(float, v00[dd] & 0xffff0000u)
                                +  w01 * __builtin_bit_cast(float, v01[dd] & 0xffff0000u)
                                +  w10 * __builtin_bit_cast(float, v10[dd] & 0xffff0000u)
                                +  w11 * __builtin_bit_cast(float, v11[dd] & 0xffff0000u);
            }
        }
        // pair reduce across the two halves (pairs differ only in bit 4 = hf)
#pragma unroll
        for (int e = 0; e < 8; ++e) acc[e] += __shfl_xor(acc[e], 16, 64);
        // both halves hold full sums; half0 stores ch 0..3, half1 stores ch 4..7
        const int ob = h * 8 + hf * 4;
        oh[qq][ob + 0] = hf ? acc[4] : acc[0];
        oh[qq][ob + 1] = hf ? acc[5] : acc[1];
        oh[qq][ob + 2] = hf ? acc[6] : acc[2];
        oh[qq][ob + 3] = hf ? acc[7] : acc[3];
        __builtin_amdgcn_s_setprio(0);
    }
    __syncthreads();

    // ---- phase D: out = oh @ W_out + b_out (hi/lo MFMA), 1 col-tile per wave
    {
        float4_t acc2 = (float4_t)(0.f);
#pragma unroll
        for (int kk = 0; kk < 4; ++kk) {
            const float4_t a0 = *(const float4_t*)&oh[m][kk * 32 + quad * 8];
            const float4_t a1 = *(const float4_t*)&oh[m][kk * 32 + quad * 8 + 4];
            short8 ahi, alo;
#pragma unroll
            for (int j = 0; j < 8; ++j) {
                const float f = (j < 4) ? a0[j] : a1[j - 4];
                const unsigned short hh = f2bf(f);
                ahi[j] = (short)hh;
                alo[j] = (short)f2bf(f - bf2f(hh));
            }
            const size_t brow = (size_t)(wv * 16 + m) * DM + kk * 32 + quad * 8;
            short8 bh = *(const short8*)(Wouth + brow);
            short8 bl = *(const short8*)(Woutl + brow);
            acc2 = __builtin_amdgcn_mfma_f32_16x16x32_bf16(ahi, bh, acc2, 0, 0, 0);
            acc2 = __builtin_amdgcn_mfma_f32_16x16x32_bf16(alo, bh, acc2, 0, 0, 0);
            acc2 = __builtin_amdgcn_mfma_f32_16x16x32_bf16(ahi, bl, acc2, 0, 0, 0);
        }
        const size_t lvl_base[3] = {0, 4194304, 5242880};
        const int col = wv * 16 + m;
        const float bb = b_out[col];
#pragma unroll
        for (int r = 0; r < 4; ++r) {
            const int qq = quad * 4 + r;
            const int gq = gq0 + qq;
            const int b = gq / LQ;
            const int q = gq - b * LQ;
            int lq, p, Hq, Wq, wshift;
            q_to_level(q, lq, p, Hq, Wq, wshift);
            const int HWq = Hq * Wq;
            out[lvl_base[lq] + ((size_t)(b * DM + col)) * HWq + p] = acc2[r] + bb;
        }
    }
}

extern "C" void kernel_launch(void* const* d_in, const int* in_sizes, int n_in,
                              void* d_out, int out_size, void* d_ws, size_t ws_size,
                              hipStream_t stream) {
    const float* fm1    = (const float*)d_in[0];
    const float* fm2    = (const float*)d_in[1];
    const float* fm3    = (const float*)d_in[2];
    const float* W_off  = (const float*)d_in[3];
    const float* b_off  = (const float*)d_in[4];
    const float* W_attn = (const float*)d_in[5];
    const float* b_attn = (const float*)d_in[6];
    const float* W_val  = (const float*)d_in[7];
    const float* b_val  = (const float*)d_in[8];
    const float* W_out  = (const float*)d_in[9];
    const float* b_out  = (const float*)d_in[10];
    float* out = (float*)d_out;

    const size_t NQ = (size_t)8 * LQ;          // 43008
    unsigned short* xh    = (unsigned short*)d_ws;      // 11,010,048 B
    unsigned short* valh  = xh + NQ * DM;               // 11,010,048 B (head-major)
    unsigned short* Wvh   = valh + NQ * DM;             // 32 KB
    unsigned short* Woa   = Wvh + 128 * 128;            // 144 KB
    unsigned short* Wouth = Woa + 576 * 128;
    unsigned short* Woutl = Wouth + 128 * 128;

    prep_k<<<5792, 256, 0, stream>>>(fm1, fm2, fm3, W_val, W_off, W_attn, W_out,
                                     xh, Wvh, Woa, Wouth, Woutl);

    value_proj_mfma<<<672, 256, 0, stream>>>(xh, Wvh, b_val, valh);

    sampler_k3<<<2688, 512, 0, stream>>>(xh, valh, Woa, b_off, b_attn,
                                         Wouth, Woutl, b_out, out);
}